// Round 1
// baseline (769.493 us; speedup 1.0000x reference)
//
#include <hip/hip_runtime.h>

#define SQ 4096
#define DMODEL 1024
#define DH 64

// XOR-style swizzle for float4-granular LDS tiles [rows][16 float4]:
// keeps lane-varying-row accesses spread across bank groups (<=2-way).
__device__ __forceinline__ int f4idx(int r, int c4) {
    return (r << 4) + ((c4 + r) & 15);
}

// ---------------------------------------------------------------------------
// Kernel 1: fused QKV projection.  x:[16384,1024] fp32, W*:[64,1024].
// Block computes 64 rows x 192 cols (Q|K|V concat).  Q pre-scaled by 1/8.
// ---------------------------------------------------------------------------
__global__ __launch_bounds__(256) void proj_kernel(
    const float* __restrict__ x,
    const float* __restrict__ Wq, const float* __restrict__ Wk, const float* __restrict__ Wv,
    const float* __restrict__ bq, const float* __restrict__ bk, const float* __restrict__ bv,
    float* __restrict__ Qo, float* __restrict__ Ko, float* __restrict__ Vo)
{
    __shared__ float4 xs4[64 * 16];    // 16 KB
    __shared__ float4 ws4[192 * 16];   // 48 KB

    const int tid = threadIdx.x;
    const int r0  = blockIdx.x << 6;
    const int rq  = tid & 15;   // row base: rows rq+16j
    const int cg  = tid >> 4;   // col base: cols cg+16i

    float acc[4][12];
    #pragma unroll
    for (int j = 0; j < 4; ++j)
        #pragma unroll
        for (int i = 0; i < 12; ++i) acc[j][i] = 0.f;

    for (int kc = 0; kc < DMODEL; kc += 64) {
        __syncthreads();
        #pragma unroll
        for (int i = 0; i < 4; ++i) {
            int id = i * 256 + tid;
            int r = id >> 4, c4 = id & 15;
            xs4[f4idx(r, c4)] = *(const float4*)&x[(r0 + r) * DMODEL + kc + c4 * 4];
        }
        #pragma unroll
        for (int i = 0; i < 12; ++i) {
            int id = i * 256 + tid;
            int c = id >> 4, k4 = id & 15;
            const float* Wrow = (c < 64)  ? (Wq + c * DMODEL)
                              : (c < 128) ? (Wk + (c - 64) * DMODEL)
                              :             (Wv + (c - 128) * DMODEL);
            ws4[f4idx(c, k4)] = *(const float4*)&Wrow[kc + k4 * 4];
        }
        __syncthreads();
        #pragma unroll 4
        for (int k4 = 0; k4 < 16; ++k4) {
            float4 a[4], bb[12];
            #pragma unroll
            for (int j = 0; j < 4; ++j) a[j] = xs4[f4idx(rq + 16 * j, k4)];
            #pragma unroll
            for (int i = 0; i < 12; ++i) bb[i] = ws4[f4idx(cg + 16 * i, k4)];
            #pragma unroll
            for (int j = 0; j < 4; ++j)
                #pragma unroll
                for (int i = 0; i < 12; ++i)
                    acc[j][i] += a[j].x * bb[i].x + a[j].y * bb[i].y
                               + a[j].z * bb[i].z + a[j].w * bb[i].w;
        }
    }

    // Transpose through LDS (reuse ws4) for coalesced float4 global stores.
    // outs logical [192 cols][64 rows], swizzled: addr = c*64 + ((r+c)&63).
    __syncthreads();
    float* outs = (float*)ws4;
    #pragma unroll
    for (int j = 0; j < 4; ++j)
        #pragma unroll
        for (int i = 0; i < 12; ++i) {
            int c = cg + 16 * i, r = rq + 16 * j;
            outs[c * 64 + ((r + c) & 63)] = acc[j][i];
        }
    __syncthreads();
    #pragma unroll
    for (int ii = 0; ii < 4; ++ii) {
        int id = ii * 256 + tid;
        int r = id >> 4, c4 = id & 15;
        float q[4], k[4], v[4];
        #pragma unroll
        for (int n = 0; n < 4; ++n) {
            int c = c4 * 4 + n;
            q[n] = (outs[c * 64 + ((r + c) & 63)] + bq[c]) * 0.125f;  // 1/sqrt(64)
            int c2 = c + 64;
            k[n] = outs[c2 * 64 + ((r + c2) & 63)] + bk[c];
            int c3 = c + 128;
            v[n] = outs[c3 * 64 + ((r + c3) & 63)] + bv[c];
        }
        int o = (r0 + r) * DH + c4 * 4;
        *(float4*)&Qo[o] = make_float4(q[0], q[1], q[2], q[3]);
        *(float4*)&Ko[o] = make_float4(k[0], k[1], k[2], k[3]);
        *(float4*)&Vo[o] = make_float4(v[0], v[1], v[2], v[3]);
    }
}

// ---------------------------------------------------------------------------
// Kernel 2: fp32 flash attention.  64-query tile / block, 64-key tiles.
// Thread (rq=tid>>4, ck=tid&15): QK fragment = rows {rq+16j} x cols {ck+16i};
// PV/output: rows {rq+16j} x d-cols {4ck..4ck+3}.  Softmax rows reduce over
// the 16 contiguous lanes sharing rq (in-wave shuffles).
// ---------------------------------------------------------------------------
__global__ __launch_bounds__(256) void attn_kernel(
    const float* __restrict__ Q, const float* __restrict__ K,
    const float* __restrict__ V, float* __restrict__ out)
{
    __shared__ float4 qs4[64 * 16];   // 16 KB
    __shared__ float4 ks4[64 * 16];   // 16 KB
    __shared__ float4 vs4[64 * 16];   // 16 KB
    __shared__ float  ps[64 * 64];    // 16 KB, swizzled: q*64 + ((k+q)&63)

    const int tid = threadIdx.x;
    const int b   = blockIdx.x >> 6;
    const int q0  = (blockIdx.x & 63) << 6;
    const int rq  = tid >> 4;
    const int ck  = tid & 15;

    const float* Qb = Q + (b * SQ + q0) * DH;
    const float* Kb = K + b * SQ * DH;
    const float* Vb = V + b * SQ * DH;

    #pragma unroll
    for (int i = 0; i < 4; ++i) {
        int id = i * 256 + tid;
        int r = id >> 4, c4 = id & 15;
        qs4[f4idx(r, c4)] = *(const float4*)&Qb[r * DH + c4 * 4];
    }

    float m[4], l[4];
    float4 o4[4];
    #pragma unroll
    for (int j = 0; j < 4; ++j) {
        m[j] = -1e30f; l[j] = 0.f;
        o4[j] = make_float4(0.f, 0.f, 0.f, 0.f);
    }

    for (int t = 0; t < SQ / 64; ++t) {
        __syncthreads();   // protect ks/vs reuse from previous PV phase
        #pragma unroll
        for (int i = 0; i < 4; ++i) {
            int id = i * 256 + tid;
            int r = id >> 4, c4 = id & 15;
            int g = (t * 64 + r) * DH + c4 * 4;
            ks4[f4idx(r, c4)] = *(const float4*)&Kb[g];
            vs4[f4idx(r, c4)] = *(const float4*)&Vb[g];
        }
        __syncthreads();

        // ---- S = Q K^T (Q pre-scaled) ----
        float4 s4[4][4];
        #pragma unroll
        for (int j = 0; j < 4; ++j)
            #pragma unroll
            for (int i = 0; i < 4; ++i) s4[j][i] = make_float4(0.f, 0.f, 0.f, 0.f);
        #pragma unroll 4
        for (int d4 = 0; d4 < 16; ++d4) {
            float4 a[4], bb[4];
            #pragma unroll
            for (int j = 0; j < 4; ++j) a[j] = qs4[f4idx(rq + 16 * j, d4)];
            #pragma unroll
            for (int i = 0; i < 4; ++i) bb[i] = ks4[f4idx(ck + 16 * i, d4)];
            #pragma unroll
            for (int j = 0; j < 4; ++j)
                #pragma unroll
                for (int i = 0; i < 4; ++i) {
                    s4[j][i].x += a[j].x * bb[i].x;
                    s4[j][i].y += a[j].y * bb[i].y;
                    s4[j][i].z += a[j].z * bb[i].z;
                    s4[j][i].w += a[j].w * bb[i].w;
                }
        }
        float s[4][4];
        #pragma unroll
        for (int j = 0; j < 4; ++j)
            #pragma unroll
            for (int i = 0; i < 4; ++i)
                s[j][i] = s4[j][i].x + s4[j][i].y + s4[j][i].z + s4[j][i].w;

        // ---- online softmax (rows live in 16-lane groups sharing rq) ----
        #pragma unroll
        for (int j = 0; j < 4; ++j) {
            float mt = fmaxf(fmaxf(s[j][0], s[j][1]), fmaxf(s[j][2], s[j][3]));
            mt = fmaxf(mt, __shfl_xor(mt, 1));
            mt = fmaxf(mt, __shfl_xor(mt, 2));
            mt = fmaxf(mt, __shfl_xor(mt, 4));
            mt = fmaxf(mt, __shfl_xor(mt, 8));
            float mn = fmaxf(m[j], mt);
            float al = __expf(m[j] - mn);
            float p0 = __expf(s[j][0] - mn);
            float p1 = __expf(s[j][1] - mn);
            float p2 = __expf(s[j][2] - mn);
            float p3 = __expf(s[j][3] - mn);
            float sum = p0 + p1 + p2 + p3;
            sum += __shfl_xor(sum, 1);
            sum += __shfl_xor(sum, 2);
            sum += __shfl_xor(sum, 4);
            sum += __shfl_xor(sum, 8);
            l[j] = l[j] * al + sum;
            m[j] = mn;
            o4[j].x *= al; o4[j].y *= al; o4[j].z *= al; o4[j].w *= al;
            int q = rq + 16 * j;
            ps[q * 64 + ((ck +  0 + q) & 63)] = p0;
            ps[q * 64 + ((ck + 16 + q) & 63)] = p1;
            ps[q * 64 + ((ck + 32 + q) & 63)] = p2;
            ps[q * 64 + ((ck + 48 + q) & 63)] = p3;
        }
        __syncthreads();

        // ---- O += P V ----
        #pragma unroll 8
        for (int k = 0; k < 64; ++k) {
            float4 v4 = vs4[f4idx(k, ck)];
            #pragma unroll
            for (int j = 0; j < 4; ++j) {
                int q = rq + 16 * j;
                float p = ps[q * 64 + ((k + q) & 63)];
                o4[j].x += p * v4.x; o4[j].y += p * v4.y;
                o4[j].z += p * v4.z; o4[j].w += p * v4.w;
            }
        }
    }

    #pragma unroll
    for (int j = 0; j < 4; ++j) {
        float inv = 1.f / l[j];
        float4 r = make_float4(o4[j].x * inv, o4[j].y * inv,
                               o4[j].z * inv, o4[j].w * inv);
        *(float4*)&out[(b * SQ + q0 + rq + 16 * j) * DH + ck * 4] = r;
    }
}

// ---------------------------------------------------------------------------
extern "C" void kernel_launch(void* const* d_in, const int* in_sizes, int n_in,
                              void* d_out, int out_size, void* d_ws, size_t ws_size,
                              hipStream_t stream) {
    const float* x  = (const float*)d_in[0];
    const float* Wq = (const float*)d_in[1];
    const float* bq = (const float*)d_in[2];
    const float* Wk = (const float*)d_in[3];
    const float* bk = (const float*)d_in[4];
    const float* Wv = (const float*)d_in[5];
    const float* bv = (const float*)d_in[6];
    float* out = (float*)d_out;

    const size_t n = (size_t)4 * SQ * DH;  // 1 Mi elements per matrix
    float* Qw = (float*)d_ws;
    float* Kw = Qw + n;
    float* Vw = Kw + n;

    proj_kernel<<<256, 256, 0, stream>>>(x, Wq, Wk, Wv, bq, bk, bv, Qw, Kw, Vw);
    attn_kernel<<<256, 256, 0, stream>>>(Qw, Kw, Vw, out);
}

// Round 2
// 304.530 us; speedup vs baseline: 2.5268x; 2.5268x over previous
//
#include <hip/hip_runtime.h>
#include <hip/hip_bf16.h>

#define SQ 4096
#define DMODEL 1024
#define DH 64
#define NQ 16384            // B*SQ
#define L2E 1.4426950408889634f

typedef __attribute__((ext_vector_type(4))) float f32x4;
typedef __attribute__((ext_vector_type(8))) short bf16x8;

// XOR-style swizzle for float4-granular LDS tiles [rows][16 float4]
__device__ __forceinline__ int f4idx(int r, int c4) {
    return (r << 4) + ((c4 + r) & 15);
}

__device__ __forceinline__ ushort bf16hi(float x) {
    return __hip_bfloat16_raw(__float2bfloat16(x)).x;
}

// ---------------------------------------------------------------------------
// Kernel 1: fused QKV projection (fp32 VALU GEMM, unchanged core).
// Outputs: Q [NQ][64] (pre-scaled by 1/8), K [NQ][64], V^T [B][64][SQ].
// ---------------------------------------------------------------------------
__global__ __launch_bounds__(256) void proj_kernel(
    const float* __restrict__ x,
    const float* __restrict__ Wq, const float* __restrict__ Wk, const float* __restrict__ Wv,
    const float* __restrict__ bq, const float* __restrict__ bk, const float* __restrict__ bv,
    float* __restrict__ Qo, float* __restrict__ Ko, float* __restrict__ Vt)
{
    __shared__ float4 xs4[64 * 16];    // 16 KB
    __shared__ float4 ws4[192 * 16];   // 48 KB

    const int tid = threadIdx.x;
    const int r0  = blockIdx.x << 6;
    const int rq  = tid & 15;
    const int cg  = tid >> 4;

    float acc[4][12];
    #pragma unroll
    for (int j = 0; j < 4; ++j)
        #pragma unroll
        for (int i = 0; i < 12; ++i) acc[j][i] = 0.f;

    for (int kc = 0; kc < DMODEL; kc += 64) {
        __syncthreads();
        #pragma unroll
        for (int i = 0; i < 4; ++i) {
            int id = i * 256 + tid;
            int r = id >> 4, c4 = id & 15;
            xs4[f4idx(r, c4)] = *(const float4*)&x[(r0 + r) * DMODEL + kc + c4 * 4];
        }
        #pragma unroll
        for (int i = 0; i < 12; ++i) {
            int id = i * 256 + tid;
            int c = id >> 4, k4 = id & 15;
            const float* Wrow = (c < 64)  ? (Wq + c * DMODEL)
                              : (c < 128) ? (Wk + (c - 64) * DMODEL)
                              :             (Wv + (c - 128) * DMODEL);
            ws4[f4idx(c, k4)] = *(const float4*)&Wrow[kc + k4 * 4];
        }
        __syncthreads();
        #pragma unroll 4
        for (int k4 = 0; k4 < 16; ++k4) {
            float4 a[4], bb[12];
            #pragma unroll
            for (int j = 0; j < 4; ++j) a[j] = xs4[f4idx(rq + 16 * j, k4)];
            #pragma unroll
            for (int i = 0; i < 12; ++i) bb[i] = ws4[f4idx(cg + 16 * i, k4)];
            #pragma unroll
            for (int j = 0; j < 4; ++j)
                #pragma unroll
                for (int i = 0; i < 12; ++i)
                    acc[j][i] += a[j].x * bb[i].x + a[j].y * bb[i].y
                               + a[j].z * bb[i].z + a[j].w * bb[i].w;
        }
    }

    __syncthreads();
    float* outs = (float*)ws4;   // [192 cols][64 rows], swizzled (r+c)&63
    #pragma unroll
    for (int j = 0; j < 4; ++j)
        #pragma unroll
        for (int i = 0; i < 12; ++i) {
            int c = cg + 16 * i, r = rq + 16 * j;
            outs[c * 64 + ((r + c) & 63)] = acc[j][i];
        }
    __syncthreads();

    const int b  = r0 >> 12;        // batch
    const int sl = r0 & (SQ - 1);   // token offset within batch

    // Q, K: [token][dh] float4 stores
    #pragma unroll
    for (int ii = 0; ii < 4; ++ii) {
        int id = ii * 256 + tid;
        int r = id >> 4, c4 = id & 15;
        float q[4], k[4];
        #pragma unroll
        for (int n = 0; n < 4; ++n) {
            int c = c4 * 4 + n;
            q[n] = (outs[c * 64 + ((r + c) & 63)] + bq[c]) * 0.125f;
            int c2 = c + 64;
            k[n] = outs[c2 * 64 + ((r + c2) & 63)] + bk[c];
        }
        int o = (r0 + r) * DH + c4 * 4;
        *(float4*)&Qo[o] = make_float4(q[0], q[1], q[2], q[3]);
        *(float4*)&Ko[o] = make_float4(k[0], k[1], k[2], k[3]);
    }
    // V^T: [b][vdim][token] float4-along-token stores
    #pragma unroll
    for (int ii = 0; ii < 4; ++ii) {
        int id = ii * 256 + tid;
        int v = id >> 4, t4 = id & 15;
        float vv[4];
        float bias = bv[v];
        #pragma unroll
        for (int n = 0; n < 4; ++n) {
            int r = t4 * 4 + n, c3 = v + 128;
            vv[n] = outs[c3 * 64 + ((r + c3) & 63)] + bias;
        }
        *(float4*)&Vt[((size_t)b * DH + v) * SQ + sl + t4 * 4] =
            make_float4(vv[0], vv[1], vv[2], vv[3]);
    }
}

// ---------------------------------------------------------------------------
// Kernel 2: MFMA flash attention, pass 1.
// Block = 4 waves, 128 queries; each wave owns 32 q (2 n-tiles of 16).
// Computes S^T = K·Q^T (split bf16, 3 terms) so both operands are natural
// row-major LDS reads; online softmax over rows of S^T; O^T += V^T·P^T
// (V split, 2 terms).  K-split over `ks` chunks; partials (O,m,l) to ws.
// ---------------------------------------------------------------------------
__global__ __launch_bounds__(256, 2) void attn_pass1(
    const float* __restrict__ Q, const float* __restrict__ K,
    const float* __restrict__ Vt,
    float* __restrict__ opart, float* __restrict__ mpart, float* __restrict__ lpart,
    float* __restrict__ out, int ks)
{
    __shared__ ushort Khi[64 * 72], Klo[64 * 72];   // 9216 B each
    __shared__ ushort Vhi[64 * 72], Vlo[64 * 72];
    __shared__ ushort Pl[4][32 * 72];               // per-wave P (bf16), 4608 B each

    const int tid   = threadIdx.x;
    const int w     = tid >> 6;
    const int l     = tid & 63;
    const int ln    = l & 15;     // lane15
    const int quad  = l >> 4;

    const int bid   = blockIdx.x;
    const int qb    = bid / ks;
    const int c     = bid - qb * ks;
    const int q0    = qb << 7;               // 128 queries
    const int b     = q0 >> 12;              // batch
    const int chunk = SQ / ks;
    const int key0  = b * SQ + c * chunk;    // global key row
    const int nIter = chunk >> 6;

    // ---- stage Q (two 64-row passes through Khi/Klo), build B-frags in regs
    bf16x8 qf[2][2][2];   // [nt][kc][hi/lo]
    #pragma unroll
    for (int pass = 0; pass < 2; ++pass) {
        __syncthreads();
        #pragma unroll
        for (int i = 0; i < 4; ++i) {
            int id = i * 256 + tid;
            int r = id >> 4, c4 = id & 15;
            float4 xv = *(const float4*)&Q[(q0 + pass * 64 + r) * DH + c4 * 4];
            ushort4 h, lo;
            float f[4] = {xv.x, xv.y, xv.z, xv.w};
            ushort hs[4], ls[4];
            #pragma unroll
            for (int n = 0; n < 4; ++n) {
                hs[n] = bf16hi(f[n]);
                __hip_bfloat16_raw hr; hr.x = hs[n];
                ls[n] = bf16hi(f[n] - __bfloat162float(__hip_bfloat16(hr)));
            }
            h  = make_ushort4(hs[0], hs[1], hs[2], hs[3]);
            lo = make_ushort4(ls[0], ls[1], ls[2], ls[3]);
            *(ushort4*)&Khi[r * 72 + c4 * 4] = h;
            *(ushort4*)&Klo[r * 72 + c4 * 4] = lo;
        }
        __syncthreads();
        if ((w >> 1) == pass) {
            int rb = (w & 1) * 32;
            #pragma unroll
            for (int nt = 0; nt < 2; ++nt)
                #pragma unroll
                for (int kc = 0; kc < 2; ++kc) {
                    int off = (rb + nt * 16 + ln) * 72 + kc * 32 + quad * 8;
                    qf[nt][kc][0] = *(bf16x8*)&Khi[off];
                    qf[nt][kc][1] = *(bf16x8*)&Klo[off];
                }
        }
    }

    float m_[2] = {-1e30f, -1e30f};
    float l_[2] = {0.f, 0.f};
    f32x4 o_[4][2];
    #pragma unroll
    for (int mt = 0; mt < 4; ++mt)
        #pragma unroll
        for (int nt = 0; nt < 2; ++nt) o_[mt][nt] = (f32x4)0.f;

    for (int it = 0; it < nIter; ++it) {
        __syncthreads();
        // ---- stage K tile [key][d] and V^T tile [vdim][key], split hi/lo
        #pragma unroll
        for (int i = 0; i < 4; ++i) {
            int id = i * 256 + tid;
            int r = id >> 4, c4 = id & 15;
            float4 kv = *(const float4*)&K[(key0 + it * 64 + r) * DH + c4 * 4];
            float4 vv = *(const float4*)&Vt[((size_t)b * DH + r) * SQ +
                                            c * chunk + it * 64 + c4 * 4];
            float kf[4] = {kv.x, kv.y, kv.z, kv.w};
            float vf[4] = {vv.x, vv.y, vv.z, vv.w};
            ushort kh[4], kl[4], vh[4], vl[4];
            #pragma unroll
            for (int n = 0; n < 4; ++n) {
                kh[n] = bf16hi(kf[n]);
                __hip_bfloat16_raw hr; hr.x = kh[n];
                kl[n] = bf16hi(kf[n] - __bfloat162float(__hip_bfloat16(hr)));
                vh[n] = bf16hi(vf[n]);
                __hip_bfloat16_raw vr; vr.x = vh[n];
                vl[n] = bf16hi(vf[n] - __bfloat162float(__hip_bfloat16(vr)));
            }
            *(ushort4*)&Khi[r * 72 + c4 * 4] = make_ushort4(kh[0], kh[1], kh[2], kh[3]);
            *(ushort4*)&Klo[r * 72 + c4 * 4] = make_ushort4(kl[0], kl[1], kl[2], kl[3]);
            *(ushort4*)&Vhi[r * 72 + c4 * 4] = make_ushort4(vh[0], vh[1], vh[2], vh[3]);
            *(ushort4*)&Vlo[r * 72 + c4 * 4] = make_ushort4(vl[0], vl[1], vl[2], vl[3]);
        }
        __syncthreads();

        // ---- S^T = K·Q^T  (rows = keys, cols = q)
        f32x4 s_[4][2];
        #pragma unroll
        for (int mt = 0; mt < 4; ++mt)
            #pragma unroll
            for (int nt = 0; nt < 2; ++nt) s_[mt][nt] = (f32x4)0.f;
        #pragma unroll
        for (int kc = 0; kc < 2; ++kc) {
            bf16x8 kah[4], kal[4];
            #pragma unroll
            for (int mt = 0; mt < 4; ++mt) {
                int off = (mt * 16 + ln) * 72 + kc * 32 + quad * 8;
                kah[mt] = *(bf16x8*)&Khi[off];
                kal[mt] = *(bf16x8*)&Klo[off];
            }
            #pragma unroll
            for (int mt = 0; mt < 4; ++mt)
                #pragma unroll
                for (int nt = 0; nt < 2; ++nt) {
                    s_[mt][nt] = __builtin_amdgcn_mfma_f32_16x16x32_bf16(
                        kah[mt], qf[nt][kc][0], s_[mt][nt], 0, 0, 0);
                    s_[mt][nt] = __builtin_amdgcn_mfma_f32_16x16x32_bf16(
                        kah[mt], qf[nt][kc][1], s_[mt][nt], 0, 0, 0);
                    s_[mt][nt] = __builtin_amdgcn_mfma_f32_16x16x32_bf16(
                        kal[mt], qf[nt][kc][0], s_[mt][nt], 0, 0, 0);
                }
        }

        // ---- online softmax over rows of S^T (keys); cols = q = ln+16nt
        #pragma unroll
        for (int nt = 0; nt < 2; ++nt) {
            float mx = -1e30f;
            #pragma unroll
            for (int mt = 0; mt < 4; ++mt)
                #pragma unroll
                for (int j = 0; j < 4; ++j) mx = fmaxf(mx, s_[mt][nt][j]);
            mx = fmaxf(mx, __shfl_xor(mx, 16));
            mx = fmaxf(mx, __shfl_xor(mx, 32));
            float mn = fmaxf(m_[nt], mx);
            float al = exp2f((m_[nt] - mn) * L2E);
            float sum = 0.f;
            #pragma unroll
            for (int mt = 0; mt < 4; ++mt)
                #pragma unroll
                for (int j = 0; j < 4; ++j) {
                    float p = exp2f((s_[mt][nt][j] - mn) * L2E);
                    s_[mt][nt][j] = p;
                    sum += p;
                }
            sum += __shfl_xor(sum, 16);
            sum += __shfl_xor(sum, 32);
            l_[nt] = l_[nt] * al + sum;
            m_[nt] = mn;
            #pragma unroll
            for (int mt = 0; mt < 4; ++mt) o_[mt][nt] *= al;
            // write P[q_local][key] bf16
            #pragma unroll
            for (int mt = 0; mt < 4; ++mt)
                #pragma unroll
                for (int j = 0; j < 4; ++j)
                    Pl[w][(ln + 16 * nt) * 72 + mt * 16 + quad * 4 + j] =
                        bf16hi(s_[mt][nt][j]);
        }
        __syncthreads();   // P visible; also keeps waves in lockstep

        // ---- O^T += V^T · P^T   (A = V^T rows, B = P rows)
        #pragma unroll
        for (int kc = 0; kc < 2; ++kc) {
            bf16x8 vah[4], val[4], pb[2];
            #pragma unroll
            for (int mt = 0; mt < 4; ++mt) {
                int off = (mt * 16 + ln) * 72 + kc * 32 + quad * 8;
                vah[mt] = *(bf16x8*)&Vhi[off];
                val[mt] = *(bf16x8*)&Vlo[off];
            }
            #pragma unroll
            for (int nt = 0; nt < 2; ++nt)
                pb[nt] = *(bf16x8*)&Pl[w][(ln + 16 * nt) * 72 + kc * 32 + quad * 8];
            #pragma unroll
            for (int mt = 0; mt < 4; ++mt)
                #pragma unroll
                for (int nt = 0; nt < 2; ++nt) {
                    o_[mt][nt] = __builtin_amdgcn_mfma_f32_16x16x32_bf16(
                        vah[mt], pb[nt], o_[mt][nt], 0, 0, 0);
                    o_[mt][nt] = __builtin_amdgcn_mfma_f32_16x16x32_bf16(
                        val[mt], pb[nt], o_[mt][nt], 0, 0, 0);
                }
        }
    }

    // ---- epilogue: transpose O^T -> [q_local][v] through LDS, store
    __syncthreads();
    float* tr = (w == 0) ? (float*)Khi : (w == 1) ? (float*)Klo
              : (w == 2) ? (float*)Vhi : (float*)Vlo;   // 9216 B >= 32*68*4
    if (ks == 1) {
        #pragma unroll
        for (int nt = 0; nt < 2; ++nt) {
            float inv = 1.f / l_[nt];
            #pragma unroll
            for (int mt = 0; mt < 4; ++mt) o_[mt][nt] *= inv;
        }
    }
    #pragma unroll
    for (int mt = 0; mt < 4; ++mt)
        #pragma unroll
        for (int nt = 0; nt < 2; ++nt)
            #pragma unroll
            for (int j = 0; j < 4; ++j)
                tr[(ln + 16 * nt) * 68 + mt * 16 + quad * 4 + j] = o_[mt][nt][j];
    __syncthreads();
    #pragma unroll
    for (int i = 0; i < 8; ++i) {
        int id = i * 64 + l;
        int row = id >> 4, c4 = id & 15;
        f32x4 val = *(f32x4*)&tr[row * 68 + c4 * 4];
        int qg = q0 + 32 * w + row;
        if (ks == 1)
            *(f32x4*)&out[qg * DH + c4 * 4] = val;
        else
            *(f32x4*)&opart[((size_t)c * NQ + qg) * DH + c4 * 4] = val;
    }
    if (ks > 1 && quad == 0) {
        #pragma unroll
        for (int nt = 0; nt < 2; ++nt) {
            int qg = q0 + 32 * w + 16 * nt + ln;
            mpart[c * NQ + qg] = m_[nt];
            lpart[c * NQ + qg] = l_[nt];
        }
    }
}

// ---------------------------------------------------------------------------
// Kernel 3: k-split combine.
// ---------------------------------------------------------------------------
__global__ __launch_bounds__(256) void attn_combine(
    const float* __restrict__ opart, const float* __restrict__ mpart,
    const float* __restrict__ lpart, float* __restrict__ out, int ks)
{
    int id = blockIdx.x * 256 + threadIdx.x;
    int q = id >> 4, c4 = id & 15;
    float M = -1e30f;
    for (int c = 0; c < ks; ++c) M = fmaxf(M, mpart[c * NQ + q]);
    float den = 0.f;
    f32x4 num = (f32x4)0.f;
    for (int c = 0; c < ks; ++c) {
        float wgt = exp2f((mpart[c * NQ + q] - M) * L2E);
        den += wgt * lpart[c * NQ + q];
        f32x4 o = *(const f32x4*)&opart[((size_t)c * NQ + q) * DH + c4 * 4];
        num += wgt * o;
    }
    float inv = 1.f / den;
    *(f32x4*)&out[q * DH + c4 * 4] = num * inv;
}

// ---------------------------------------------------------------------------
extern "C" void kernel_launch(void* const* d_in, const int* in_sizes, int n_in,
                              void* d_out, int out_size, void* d_ws, size_t ws_size,
                              hipStream_t stream) {
    const float* x  = (const float*)d_in[0];
    const float* Wq = (const float*)d_in[1];
    const float* bq = (const float*)d_in[2];
    const float* Wk = (const float*)d_in[3];
    const float* bk = (const float*)d_in[4];
    const float* Wv = (const float*)d_in[5];
    const float* bv = (const float*)d_in[6];
    float* out = (float*)d_out;

    const size_t n = (size_t)NQ * DH;   // 1 Mi elements
    float* Qw = (float*)d_ws;
    float* Kw = Qw + n;
    float* Vt = Kw + n;

    // k-split factor, gated on workspace size
    const int KS = 4;
    size_t need = (3 * n + (size_t)KS * n + 2 * (size_t)KS * NQ) * sizeof(float);
    int ks = (ws_size >= need) ? KS : 1;

    float* opart = Vt + n;
    float* mpart = opart + (size_t)ks * n;
    float* lpart = mpart + (size_t)ks * NQ;

    proj_kernel<<<256, 256, 0, stream>>>(x, Wq, Wk, Wv, bq, bk, bv, Qw, Kw, Vt);
    attn_pass1<<<(NQ / 128) * ks, 256, 0, stream>>>(Qw, Kw, Vt, opart, mpart, lpart,
                                                    out, ks);
    if (ks > 1)
        attn_combine<<<(NQ * 16) / 256, 256, 0, stream>>>(opart, mpart, lpart, out, ks);
}

// Round 3
// 198.724 us; speedup vs baseline: 3.8722x; 1.5324x over previous
//
#include <hip/hip_runtime.h>

typedef unsigned int uint;
typedef unsigned short ushort;

#define SQ 4096
#define DMODEL 1024
#define DH 64
#define NQ 16384            // B*SQ
#define L2E 1.4426950408889634f

typedef __attribute__((ext_vector_type(4))) float f32x4;
typedef __attribute__((ext_vector_type(8))) short bf16x8;

// ---- helpers ---------------------------------------------------------------

// async 16B/lane global->LDS copy; lds base must be wave-uniform
__device__ __forceinline__ void ld_lds16(const ushort* g, ushort* l) {
    __builtin_amdgcn_global_load_lds(
        (const __attribute__((address_space(1))) void*)g,
        (__attribute__((address_space(3))) void*)l, 16, 0, 0);
}

// split x into bf16 hi (truncated) + bf16 lo (exact remainder, truncated):
// hi exact-compensated by lo; dropped precision ~2^-17 relative.
__device__ __forceinline__ void split2(float x, ushort& h, ushort& l) {
    uint u = __float_as_uint(x);
    float lof = x - __uint_as_float(u & 0xffff0000u);
    h = (ushort)(u >> 16);
    l = (ushort)(__float_as_uint(lof) >> 16);
}

// pack two floats to two RNE bf16 in one uint (a in low 16, b in high 16)
__device__ __forceinline__ uint bfpack_rne(float a, float b) {
    uint ua = __float_as_uint(a);
    ua = (ua + 0x7fffu + ((ua >> 16) & 1u)) >> 16;
    uint ub = __float_as_uint(b);
    ub = (ub + 0x7fffu + ((ub >> 16) & 1u)) & 0xffff0000u;
    return ua | ub;
}

// ---------------------------------------------------------------------------
// Kernel 0: split W (Q|K|V concat, 192 rows x 1024) into bf16 hi/lo, laid out
// per 64-k chunk as [chunk][192 rows][8 granules ^ (r&7)][8 shorts] so a proj
// chunk-tile is 24 KB contiguous and global_load_lds lands it pre-swizzled.
// ---------------------------------------------------------------------------
__global__ __launch_bounds__(256) void wsplit_kernel(
    const float* __restrict__ Wq, const float* __restrict__ Wk,
    const float* __restrict__ Wv,
    ushort* __restrict__ Wch, ushort* __restrict__ Wcl)
{
    int r = blockIdx.x;              // 0..191
    int k = threadIdx.x * 4;         // 0..1020
    const float* src = (r < 64)  ? (Wq + r * DMODEL)
                     : (r < 128) ? (Wk + (r - 64) * DMODEL)
                     :             (Wv + (r - 128) * DMODEL);
    float4 v = *(const float4*)&src[k];
    ushort h[4], l[4];
    split2(v.x, h[0], l[0]); split2(v.y, h[1], l[1]);
    split2(v.z, h[2], l[2]); split2(v.w, h[3], l[3]);
    int ch = k >> 6, kl = k & 63;
    int g = kl >> 3;
    int idx = ch * 12288 + r * 64 + ((g ^ (r & 7)) << 3) + (kl & 7);
    *(ushort4*)&Wch[idx] = make_ushort4(h[0], h[1], h[2], h[3]);
    *(ushort4*)&Wcl[idx] = make_ushort4(l[0], l[1], l[2], l[3]);
}

// ---------------------------------------------------------------------------
// Kernel 1: fused QKV projection, split-bf16 MFMA (3-term: XhWh+XhWl+XlWh).
// Block: 64 M-rows x 192 N.  Outputs pre-split + pre-swizzled bf16 tiles:
//   Qh/Ql,Kh/Kl: [NQ/64 tiles][64 r][8 gran ^ (r&7)][8]   (Q pre-scaled 1/8)
//   Vh/Vl:       [B*64 tiles][64 v][8 gran ^ (v&7)][8]    (token tiles of 64)
// ---------------------------------------------------------------------------
__global__ __launch_bounds__(256, 2) void proj_kernel(
    const float* __restrict__ x,
    const ushort* __restrict__ Wch, const ushort* __restrict__ Wcl,
    const float* __restrict__ bq, const float* __restrict__ bk,
    const float* __restrict__ bv,
    ushort* __restrict__ Qh, ushort* __restrict__ Ql,
    ushort* __restrict__ Kh, ushort* __restrict__ Kl,
    ushort* __restrict__ Vh, ushort* __restrict__ Vl)
{
    __shared__ ushort sm[32768];     // 64 KB
    ushort* Xh = sm;                 // 4096 shorts
    ushort* Xl = sm + 4096;
    ushort* Wh = sm + 8192;          // 12288 shorts
    ushort* Wl = sm + 20480;

    const int tid  = threadIdx.x;
    const int w    = tid >> 6;
    const int l    = tid & 63;
    const int ln   = l & 15;
    const int quad = l >> 4;
    const int r0   = blockIdx.x << 6;

    f32x4 o_[4][3];
    #pragma unroll
    for (int mt = 0; mt < 4; ++mt)
        #pragma unroll
        for (int nt = 0; nt < 3; ++nt) o_[mt][nt] = (f32x4)0.f;

    for (int ch = 0; ch < 16; ++ch) {
        __syncthreads();
        // stage X (convert fp32 -> hi/lo, swizzled)
        #pragma unroll
        for (int i = 0; i < 4; ++i) {
            int id = i * 256 + tid;
            int r = id >> 4, c4 = id & 15;
            float4 xv = *(const float4*)&x[(r0 + r) * DMODEL + ch * 64 + c4 * 4];
            ushort h0, h1, h2, h3, l0, l1, l2, l3;
            split2(xv.x, h0, l0); split2(xv.y, h1, l1);
            split2(xv.z, h2, l2); split2(xv.w, h3, l3);
            int idx = r * 64 + (((c4 >> 1) ^ (r & 7)) << 3) + (c4 & 1) * 4;
            *(ushort4*)&Xh[idx] = make_ushort4(h0, h1, h2, h3);
            *(ushort4*)&Xl[idx] = make_ushort4(l0, l1, l2, l3);
        }
        // stage W via async copy (already split + swizzled in global)
        {
            const ushort* gh = Wch + ch * 12288 + w * 3072 + l * 8;
            const ushort* gl = Wcl + ch * 12288 + w * 3072 + l * 8;
            #pragma unroll
            for (int i = 0; i < 6; ++i) {
                ld_lds16(gh + i * 512, Wh + w * 3072 + i * 512);
                ld_lds16(gl + i * 512, Wl + w * 3072 + i * 512);
            }
        }
        __syncthreads();
        #pragma unroll
        for (int kc = 0; kc < 2; ++kc) {
            int gsw = ((kc * 4 + quad) ^ (ln & 7)) << 3;
            bf16x8 xh[4], xl[4], wh[3], wl[3];
            #pragma unroll
            for (int mt = 0; mt < 4; ++mt) {
                int off = (mt * 16 + ln) * 64 + gsw;
                xh[mt] = *(bf16x8*)&Xh[off];
                xl[mt] = *(bf16x8*)&Xl[off];
            }
            #pragma unroll
            for (int nt = 0; nt < 3; ++nt) {
                int off = (w * 48 + nt * 16 + ln) * 64 + gsw;
                wh[nt] = *(bf16x8*)&Wh[off];
                wl[nt] = *(bf16x8*)&Wl[off];
            }
            #pragma unroll
            for (int mt = 0; mt < 4; ++mt)
                #pragma unroll
                for (int nt = 0; nt < 3; ++nt) {
                    o_[mt][nt] = __builtin_amdgcn_mfma_f32_16x16x32_bf16(
                        xh[mt], wh[nt], o_[mt][nt], 0, 0, 0);
                    o_[mt][nt] = __builtin_amdgcn_mfma_f32_16x16x32_bf16(
                        xh[mt], wl[nt], o_[mt][nt], 0, 0, 0);
                    o_[mt][nt] = __builtin_amdgcn_mfma_f32_16x16x32_bf16(
                        xl[mt], wh[nt], o_[mt][nt], 0, 0, 0);
                }
        }
    }

    // ---- epilogue: bias+scale, split hi/lo, transpose via LDS, store tiles
    __syncthreads();
    uint* Oqk = (uint*)sm;           // [64 m][128 n] packed (hi|lo<<16)
    uint* Ov  = (uint*)sm + 8192;    // [64 v][64 m ^ ((v&7)<<2)]
    #pragma unroll
    for (int nt = 0; nt < 3; ++nt) {
        int col = 16 * (3 * w + nt) + ln;
        float bias, scl;
        if (col < 64)       { bias = bq[col];       scl = 0.125f; }
        else if (col < 128) { bias = bk[col - 64];  scl = 1.f; }
        else                { bias = bv[col - 128]; scl = 1.f; }
        #pragma unroll
        for (int mt = 0; mt < 4; ++mt)
            #pragma unroll
            for (int j = 0; j < 4; ++j) {
                int m = mt * 16 + quad * 4 + j;
                float val = (o_[mt][nt][j] + bias) * scl;
                uint u = __float_as_uint(val);
                float lof = val - __uint_as_float(u & 0xffff0000u);
                uint entry = (__float_as_uint(lof) & 0xffff0000u) | (u >> 16);
                if (col < 128) Oqk[m * 128 + col] = entry;
                else {
                    int v = col - 128;
                    Ov[v * 64 + (m ^ ((v & 7) << 2))] = entry;
                }
            }
    }
    __syncthreads();
    const int tile_qk = r0 >> 6;
    #pragma unroll
    for (int i = 0; i < 8; ++i) {
        int id = i * 256 + tid;
        int m = id >> 5, g = id & 31;
        uint4 e = *(uint4*)&Oqk[m * 128 + g * 4];
        uint h0 = (e.x & 0xffffu) | (e.y << 16);
        uint h1 = (e.z & 0xffffu) | (e.w << 16);
        uint l0 = (e.x >> 16) | (e.y & 0xffff0000u);
        uint l1 = (e.z >> 16) | (e.w & 0xffff0000u);
        int gg = g & 15;
        int idx = tile_qk * 4096 + m * 64 + (((gg >> 1) ^ (m & 7)) << 3) + (gg & 1) * 4;
        uint2 hh; hh.x = h0; hh.y = h1;
        uint2 llv; llv.x = l0; llv.y = l1;
        if (g < 16) { *(uint2*)&Qh[idx] = hh; *(uint2*)&Ql[idx] = llv; }
        else        { *(uint2*)&Kh[idx] = hh; *(uint2*)&Kl[idx] = llv; }
    }
    const int b  = r0 >> 12;
    const int vt = b * 64 + ((r0 & (SQ - 1)) >> 6);
    #pragma unroll
    for (int i = 0; i < 4; ++i) {
        int id = i * 256 + tid;
        int v = id >> 4, gm = id & 15;
        uint4 e = *(uint4*)&Ov[v * 64 + 4 * (gm ^ (v & 7))];
        uint h0 = (e.x & 0xffffu) | (e.y << 16);
        uint h1 = (e.z & 0xffffu) | (e.w << 16);
        uint l0 = (e.x >> 16) | (e.y & 0xffff0000u);
        uint l1 = (e.z >> 16) | (e.w & 0xffff0000u);
        int idx = vt * 4096 + v * 64 + (((gm >> 1) ^ (v & 7)) << 3) + (gm & 1) * 4;
        uint2 hh; hh.x = h0; hh.y = h1;
        uint2 llv; llv.x = l0; llv.y = l1;
        *(uint2*)&Vh[idx] = hh; *(uint2*)&Vl[idx] = llv;
    }
}

// ---------------------------------------------------------------------------
// Kernel 2: MFMA flash attention; all staging via global_load_lds from the
// pre-split, pre-swizzled tiles.  Block = 4 waves, 128 q; K-split over ks.
// ---------------------------------------------------------------------------
__global__ __launch_bounds__(256, 3) void attn_kernel(
    const ushort* __restrict__ Qh, const ushort* __restrict__ Ql,
    const ushort* __restrict__ Kh, const ushort* __restrict__ Kl,
    const ushort* __restrict__ Vh, const ushort* __restrict__ Vl,
    float* __restrict__ opart, float* __restrict__ mpart,
    float* __restrict__ lpart, float* __restrict__ out, int ks)
{
    __shared__ ushort As[24576];     // 48 KB
    ushort* Khs = As;                // 4096 each
    ushort* Kls = As + 4096;
    ushort* Vhs = As + 8192;
    ushort* Vls = As + 12288;
    ushort* Ps  = As + 16384;        // + w*2048

    const int tid  = threadIdx.x;
    const int w    = tid >> 6;
    const int l    = tid & 63;
    const int ln   = l & 15;
    const int quad = l >> 4;

    const int bid   = blockIdx.x;
    const int qb    = bid / ks;
    const int c     = bid - qb * ks;
    const int q0    = qb << 7;
    const int b     = q0 >> 12;
    const int chunk = SQ / ks;
    const int tile0 = (b * SQ + c * chunk) >> 6;
    const int vt0   = b * 64 + ((c * chunk) >> 6);
    const int nIter = chunk >> 6;

    // ---- stage Q (2 passes through Khs/Kls), build B-frags
    bf16x8 qf[2][2][2];              // [nt][kc][hi/lo]
    #pragma unroll
    for (int pass = 0; pass < 2; ++pass) {
        if (pass) __syncthreads();
        int qt = (q0 >> 6) + pass;
        const ushort* gh = Qh + qt * 4096 + w * 1024 + l * 8;
        const ushort* gl = Ql + qt * 4096 + w * 1024 + l * 8;
        ld_lds16(gh,       Khs + w * 1024);
        ld_lds16(gh + 512, Khs + w * 1024 + 512);
        ld_lds16(gl,       Kls + w * 1024);
        ld_lds16(gl + 512, Kls + w * 1024 + 512);
        __syncthreads();
        if ((w >> 1) == pass) {
            int rb = (w & 1) * 32;
            #pragma unroll
            for (int nt = 0; nt < 2; ++nt)
                #pragma unroll
                for (int kc = 0; kc < 2; ++kc) {
                    int off = (rb + nt * 16 + ln) * 64 +
                              (((kc * 4 + quad) ^ (ln & 7)) << 3);
                    qf[nt][kc][0] = *(bf16x8*)&Khs[off];
                    qf[nt][kc][1] = *(bf16x8*)&Kls[off];
                }
        }
    }

    float m_[2] = {-1e30f, -1e30f};
    float l_[2] = {0.f, 0.f};
    f32x4 o_[4][2];
    #pragma unroll
    for (int mt = 0; mt < 4; ++mt)
        #pragma unroll
        for (int nt = 0; nt < 2; ++nt) o_[mt][nt] = (f32x4)0.f;

    for (int it = 0; it < nIter; ++it) {
        __syncthreads();
        {
            int kt = (tile0 + it) * 4096 + w * 1024 + l * 8;
            int vt = (vt0 + it) * 4096 + w * 1024 + l * 8;
            ld_lds16(Kh + kt,       Khs + w * 1024);
            ld_lds16(Kh + kt + 512, Khs + w * 1024 + 512);
            ld_lds16(Kl + kt,       Kls + w * 1024);
            ld_lds16(Kl + kt + 512, Kls + w * 1024 + 512);
            ld_lds16(Vh + vt,       Vhs + w * 1024);
            ld_lds16(Vh + vt + 512, Vhs + w * 1024 + 512);
            ld_lds16(Vl + vt,       Vls + w * 1024);
            ld_lds16(Vl + vt + 512, Vls + w * 1024 + 512);
        }
        __syncthreads();

        // ---- S^T = K·Q^T (3-term split)
        f32x4 s_[4][2];
        #pragma unroll
        for (int mt = 0; mt < 4; ++mt)
            #pragma unroll
            for (int nt = 0; nt < 2; ++nt) s_[mt][nt] = (f32x4)0.f;
        #pragma unroll
        for (int kc = 0; kc < 2; ++kc) {
            int gsw = ((kc * 4 + quad) ^ (ln & 7)) << 3;
            bf16x8 kah[4], kal[4];
            #pragma unroll
            for (int mt = 0; mt < 4; ++mt) {
                int off = (mt * 16 + ln) * 64 + gsw;
                kah[mt] = *(bf16x8*)&Khs[off];
                kal[mt] = *(bf16x8*)&Kls[off];
            }
            #pragma unroll
            for (int mt = 0; mt < 4; ++mt)
                #pragma unroll
                for (int nt = 0; nt < 2; ++nt) {
                    s_[mt][nt] = __builtin_amdgcn_mfma_f32_16x16x32_bf16(
                        kah[mt], qf[nt][kc][0], s_[mt][nt], 0, 0, 0);
                    s_[mt][nt] = __builtin_amdgcn_mfma_f32_16x16x32_bf16(
                        kah[mt], qf[nt][kc][1], s_[mt][nt], 0, 0, 0);
                    s_[mt][nt] = __builtin_amdgcn_mfma_f32_16x16x32_bf16(
                        kal[mt], qf[nt][kc][0], s_[mt][nt], 0, 0, 0);
                }
        }

        // ---- online softmax (rows = keys in-frag, cols = q = ln+16nt)
        #pragma unroll
        for (int nt = 0; nt < 2; ++nt) {
            float mx = -1e30f;
            #pragma unroll
            for (int mt = 0; mt < 4; ++mt)
                #pragma unroll
                for (int j = 0; j < 4; ++j) mx = fmaxf(mx, s_[mt][nt][j]);
            mx = fmaxf(mx, __shfl_xor(mx, 16));
            mx = fmaxf(mx, __shfl_xor(mx, 32));
            float mn = fmaxf(m_[nt], mx);
            float al = exp2f((m_[nt] - mn) * L2E);
            float sum = 0.f;
            #pragma unroll
            for (int mt = 0; mt < 4; ++mt)
                #pragma unroll
                for (int j = 0; j < 4; ++j) {
                    float p = exp2f((s_[mt][nt][j] - mn) * L2E);
                    s_[mt][nt][j] = p;
                    sum += p;
                }
            sum += __shfl_xor(sum, 16);
            sum += __shfl_xor(sum, 32);
            l_[nt] = l_[nt] * al + sum;
            m_[nt] = mn;
            #pragma unroll
            for (int mt = 0; mt < 4; ++mt) o_[mt][nt] *= al;
            int q = ln + 16 * nt;
            ushort* Pw = Ps + w * 2048 + q * 64;
            int sw = q & 7;
            #pragma unroll
            for (int mt = 0; mt < 4; ++mt) {
                uint e0 = bfpack_rne(s_[mt][nt][0], s_[mt][nt][1]);
                uint e1 = bfpack_rne(s_[mt][nt][2], s_[mt][nt][3]);
                int g = 2 * mt + (quad >> 1);
                int idx = ((g ^ sw) << 3) + (quad & 1) * 4;
                uint2 e; e.x = e0; e.y = e1;
                *(uint2*)&Pw[idx] = e;
            }
        }
        // P is per-wave: no barrier needed (wave-local lgkmcnt ordering)

        // ---- O^T += V^T·P^T (2-term split)
        #pragma unroll
        for (int kc = 0; kc < 2; ++kc) {
            int gsw = ((kc * 4 + quad) ^ (ln & 7)) << 3;
            bf16x8 vah[4], vav[4], pb[2];
            #pragma unroll
            for (int mt = 0; mt < 4; ++mt) {
                int off = (mt * 16 + ln) * 64 + gsw;
                vah[mt] = *(bf16x8*)&Vhs[off];
                vav[mt] = *(bf16x8*)&Vls[off];
            }
            #pragma unroll
            for (int nt = 0; nt < 2; ++nt)
                pb[nt] = *(bf16x8*)&Ps[w * 2048 + (ln + 16 * nt) * 64 + gsw];
            #pragma unroll
            for (int mt = 0; mt < 4; ++mt)
                #pragma unroll
                for (int nt = 0; nt < 2; ++nt) {
                    o_[mt][nt] = __builtin_amdgcn_mfma_f32_16x16x32_bf16(
                        vah[mt], pb[nt], o_[mt][nt], 0, 0, 0);
                    o_[mt][nt] = __builtin_amdgcn_mfma_f32_16x16x32_bf16(
                        vav[mt], pb[nt], o_[mt][nt], 0, 0, 0);
                }
        }
    }

    // ---- epilogue: per-wave LDS transpose (16 q rows per pass), store
    __syncthreads();
    float* tr = (float*)(As + w * 4096);   // 8 KB per wave
    if (ks == 1) {
        #pragma unroll
        for (int nt = 0; nt < 2; ++nt) {
            float inv = 1.f / l_[nt];
            #pragma unroll
            for (int mt = 0; mt < 4; ++mt) o_[mt][nt] *= inv;
        }
    }
    #pragma unroll
    for (int p = 0; p < 2; ++p) {
        #pragma unroll
        for (int mt = 0; mt < 4; ++mt)
            #pragma unroll
            for (int j = 0; j < 4; ++j)
                tr[(ln * 16 + ((mt * 4 + quad) ^ ln)) * 4 + j] = o_[mt][p][j];
        #pragma unroll
        for (int i2 = 0; i2 < 4; ++i2) {
            int qt = i2 * 4 + quad;
            f32x4 vv = *(f32x4*)&tr[(qt * 16 + (ln ^ qt)) * 4];
            int qg = q0 + w * 32 + p * 16 + qt;
            if (ks == 1) *(f32x4*)&out[qg * DH + ln * 4] = vv;
            else *(f32x4*)&opart[((size_t)c * NQ + qg) * DH + ln * 4] = vv;
        }
    }
    if (ks > 1 && quad == 0) {
        #pragma unroll
        for (int nt = 0; nt < 2; ++nt) {
            int qg = q0 + w * 32 + 16 * nt + ln;
            mpart[c * NQ + qg] = m_[nt];
            lpart[c * NQ + qg] = l_[nt];
        }
    }
}

// ---------------------------------------------------------------------------
// Kernel 3: k-split combine.
// ---------------------------------------------------------------------------
__global__ __launch_bounds__(256) void attn_combine(
    const float* __restrict__ opart, const float* __restrict__ mpart,
    const float* __restrict__ lpart, float* __restrict__ out, int ks)
{
    int id = blockIdx.x * 256 + threadIdx.x;
    int q = id >> 4, c4 = id & 15;
    float M = -1e30f;
    for (int c = 0; c < ks; ++c) M = fmaxf(M, mpart[c * NQ + q]);
    float den = 0.f;
    f32x4 num = (f32x4)0.f;
    for (int c = 0; c < ks; ++c) {
        float wgt = exp2f((mpart[c * NQ + q] - M) * L2E);
        den += wgt * lpart[c * NQ + q];
        f32x4 o = *(const f32x4*)&opart[((size_t)c * NQ + q) * DH + c4 * 4];
        num += wgt * o;
    }
    float inv = 1.f / den;
    *(f32x4*)&out[q * DH + c4 * 4] = num * inv;
}

// ---------------------------------------------------------------------------
extern "C" void kernel_launch(void* const* d_in, const int* in_sizes, int n_in,
                              void* d_out, int out_size, void* d_ws, size_t ws_size,
                              hipStream_t stream) {
    const float* x  = (const float*)d_in[0];
    const float* Wq = (const float*)d_in[1];
    const float* bq = (const float*)d_in[2];
    const float* Wk = (const float*)d_in[3];
    const float* bk = (const float*)d_in[4];
    const float* Wv = (const float*)d_in[5];
    const float* bv = (const float*)d_in[6];
    float* out = (float*)d_out;

    const size_t n16 = (size_t)NQ * DH;      // shorts per bf16 array (1 Mi)
    char* p = (char*)d_ws;
    ushort* Qh = (ushort*)p;           p += n16 * 2;
    ushort* Ql = (ushort*)p;           p += n16 * 2;
    ushort* Kh = (ushort*)p;           p += n16 * 2;
    ushort* Kl = (ushort*)p;           p += n16 * 2;
    ushort* Vh = (ushort*)p;           p += n16 * 2;
    ushort* Vl = (ushort*)p;           p += n16 * 2;
    ushort* Wch = (ushort*)p;          p += 192 * 1024 * 2;
    ushort* Wcl = (ushort*)p;          p += 192 * 1024 * 2;

    const int KS = 4;
    size_t base = (size_t)(p - (char*)d_ws);
    size_t need4 = base + (size_t)KS * n16 * 4 + 2ul * KS * NQ * 4;
    int ks = (ws_size >= need4) ? KS : 1;

    float* opart = (float*)p;          p += (size_t)ks * n16 * 4;
    float* mpart = (float*)p;          p += (size_t)ks * NQ * 4;
    float* lpart = (float*)p;

    wsplit_kernel<<<192, 256, 0, stream>>>(Wq, Wk, Wv, Wch, Wcl);
    proj_kernel<<<NQ / 64, 256, 0, stream>>>(x, Wch, Wcl, bq, bk, bv,
                                             Qh, Ql, Kh, Kl, Vh, Vl);
    attn_kernel<<<(NQ / 128) * ks, 256, 0, stream>>>(
        Qh, Ql, Kh, Kl, Vh, Vl, opart, mpart, lpart, out, ks);
    if (ks > 1)
        attn_combine<<<(NQ * 16) / 256, 256, 0, stream>>>(opart, mpart, lpart,
                                                          out, ks);
}